// Round 1
// baseline (2687.701 us; speedup 1.0000x reference)
//
#include <hip/hip_runtime.h>
#include <hip/hip_bf16.h>
#include <stdint.h>

#define BT 2048
#define HS 2048      // student hidden (H/2)
#define HT 4096      // teacher hidden (H)
#define NVOCAB 32000
#define IGN (-100)

typedef unsigned short u16;
typedef __attribute__((ext_vector_type(4))) float f32x4;
typedef __attribute__((ext_vector_type(8))) short short8;
typedef __attribute__((ext_vector_type(2))) unsigned int u32x2;
typedef __attribute__((ext_vector_type(4))) unsigned int u32x4;

// ---------- helpers ----------
__device__ inline unsigned int pack2_bf16(float a, float b) {
  union { __hip_bfloat162 h; unsigned int u; } cv;
  cv.h = __float22bfloat162_rn(make_float2(a, b));
  return cv.u;
}

__device__ inline void async16(const void* g, void* l) {
  __builtin_amdgcn_global_load_lds(
      (const __attribute__((address_space(1))) void*)g,
      (__attribute__((address_space(3))) void*)l, 16, 0, 0);
}

// ---------- fp32 -> bf16 convert (activations only) ----------
__global__ void cvt_f32_bf16(const float4* __restrict__ in, u32x2* __restrict__ out, int n4) {
  int i = blockIdx.x * blockDim.x + threadIdx.x;
  if (i >= n4) return;
  float4 v = in[i];
  u32x2 o;
  o.x = pack2_bf16(v.x, v.y);
  o.y = pack2_bf16(v.z, v.w);
  out[i] = o;
}

// ---------- one NT-GEMM phase: acc[4][4] += A[128 x K] * B[128 x K]^T ----------
// A: bf16 row-major (lda), base at (row0, 0). Staged via global_load_lds.
// B: fp32 row-major (ldb), base at (col0, 0). Staged via reg->cvt->ds_write.
__device__ inline void gemm_nt(const u16* __restrict__ A, int lda,
                               const float* __restrict__ B, int ldb, int K,
                               u16* stA, u16* stB, f32x4 (&acc)[4][4]) {
  const int tid = threadIdx.x;
  const int lane = tid & 63;
  const int w = tid >> 6;
  const int wr = w >> 1, wc = w & 1;
  const int q = lane >> 4, l15 = lane & 15;

  // A async-load mapping: chunk = w*2+c; row = chunk*16 + lane/4; kOff = (lane&3)*8
  const u16* aPtr0 = A + (size_t)(w * 32 + (lane >> 2)) * lda + ((lane & 3) * 8);
  const u16* aPtr1 = aPtr0 + (size_t)16 * lda;
  u16* ldsA0 = stA + (size_t)(w * 2) * 512;      // 512 u16 = 1KB per chunk
  u16* ldsA1 = stA + (size_t)(w * 2 + 1) * 512;

  // B staging mapping: row = tid>>1 (local col), half = tid&1 covers 16 floats
  const float* bPtr = B + (size_t)(tid >> 1) * ldb + (tid & 1) * 16;
  u16* ldsBw = stB + (tid >> 1) * 32 + (tid & 1) * 16;

  for (int k0 = 0; k0 < K; k0 += 32) {
    __syncthreads();  // previous tile fully consumed
    // A tile (128x32 bf16, 8KB) via async global->LDS
    async16(aPtr0 + k0, ldsA0);
    async16(aPtr1 + k0, ldsA1);
    // B tile (128x32 fp32 -> bf16)
    const float4* bp = (const float4*)(bPtr + k0);
    float4 f0 = bp[0], f1 = bp[1], f2 = bp[2], f3 = bp[3];
    u32x4 w0, w1;
    w0.x = pack2_bf16(f0.x, f0.y); w0.y = pack2_bf16(f0.z, f0.w);
    w0.z = pack2_bf16(f1.x, f1.y); w0.w = pack2_bf16(f1.z, f1.w);
    w1.x = pack2_bf16(f2.x, f2.y); w1.y = pack2_bf16(f2.z, f2.w);
    w1.z = pack2_bf16(f3.x, f3.y); w1.w = pack2_bf16(f3.z, f3.w);
    ((u32x4*)ldsBw)[0] = w0;
    ((u32x4*)ldsBw)[1] = w1;
    __syncthreads();  // tile visible (compiler drains vmcnt+lgkmcnt)

    short8 af[4], bf[4];
#pragma unroll
    for (int f = 0; f < 4; f++)
      af[f] = *(const short8*)&stA[(wr * 64 + f * 16 + l15) * 32 + q * 8];
#pragma unroll
    for (int f = 0; f < 4; f++)
      bf[f] = *(const short8*)&stB[(wc * 64 + f * 16 + l15) * 32 + q * 8];
#pragma unroll
    for (int i = 0; i < 4; i++)
#pragma unroll
      for (int j = 0; j < 4; j++)
        acc[i][j] = __builtin_amdgcn_mfma_f32_16x16x32_bf16(af[i], bf[j], acc[i][j], 0, 0, 0);
  }
}

// ---------- fused dual-GEMM + epilogue ----------
__global__ __launch_bounds__(256) void kmain(
    const u16* __restrict__ sAb, const u16* __restrict__ tAb,
    const float* __restrict__ sW, const float* __restrict__ tW,
    const int* __restrict__ target,
    float* __restrict__ pe, float* __restrict__ ps,
    float* __restrict__ pt, float* __restrict__ pd,
    float* __restrict__ tgtLogit) {
  __shared__ u16 stA[128 * 32];
  __shared__ u16 stB[128 * 32];
  __shared__ u16 sStore[128 * 132];  // [col][row] bf16, row-pitch 132 (pad: bank spread)
  __shared__ int tgtLds[128];

  const int bid = blockIdx.x;
  const int cb = bid >> 4;   // 0..249  (16 consecutive blocks share the weight strip)
  const int rb = bid & 15;   // 0..15
  const int row0 = rb * 128;
  const int col0 = cb * 128;

  const int tid = threadIdx.x;
  const int lane = tid & 63;
  const int w = tid >> 6;
  const int wr = w >> 1, wc = w & 1;
  const int l15 = lane & 15;
  const int q4 = (lane >> 4) << 2;

  if (tid < 128) tgtLds[tid] = target[row0 + tid];

  f32x4 acc[4][4];
#pragma unroll
  for (int i = 0; i < 4; i++)
#pragma unroll
    for (int j = 0; j < 4; j++) acc[i][j] = (f32x4){0.f, 0.f, 0.f, 0.f};

  // ===== student GEMM =====
  gemm_nt(sAb + (size_t)row0 * HS, HS, sW + (size_t)col0 * HS, HS, HS, stA, stB, acc);

  // ===== epilogue 1: expsum, sumsq_s, target logit, stash s (bf16) =====
#pragma unroll
  for (int fr = 0; fr < 4; fr++) {
    const int r0 = wr * 64 + fr * 16 + q4;
    float se[4] = {0.f, 0.f, 0.f, 0.f}, sq[4] = {0.f, 0.f, 0.f, 0.f};
#pragma unroll
    for (int fc = 0; fc < 4; fc++) {
      f32x4 v = acc[fr][fc];
      const int cLoc = wc * 64 + fc * 16 + l15;
      const int cGlob = col0 + cLoc;
      u32x2 pk;
      pk.x = pack2_bf16(v[0], v[1]);
      pk.y = pack2_bf16(v[2], v[3]);
      *(u32x2*)&sStore[cLoc * 132 + r0] = pk;
#pragma unroll
      for (int rg = 0; rg < 4; rg++) {
        float x = v[rg];
        se[rg] += __expf(x);
        sq[rg] += x * x;
        if (tgtLds[r0 + rg] == cGlob) tgtLogit[row0 + r0 + rg] = x;
      }
    }
#pragma unroll
    for (int m = 1; m < 16; m <<= 1) {
#pragma unroll
      for (int rg = 0; rg < 4; rg++) {
        se[rg] += __shfl_xor(se[rg], m, 64);
        sq[rg] += __shfl_xor(sq[rg], m, 64);
      }
    }
    if (l15 == 0) {
      size_t pbase = (size_t)(cb * 2 + wc) * BT + row0 + r0;
#pragma unroll
      for (int rg = 0; rg < 4; rg++) {
        pe[pbase + rg] = se[rg];
        ps[pbase + rg] = sq[rg];
      }
    }
  }

  // ===== teacher GEMM =====
#pragma unroll
  for (int i = 0; i < 4; i++)
#pragma unroll
    for (int j = 0; j < 4; j++) acc[i][j] = (f32x4){0.f, 0.f, 0.f, 0.f};
  gemm_nt(tAb + (size_t)row0 * HT, HT, tW + (size_t)col0 * HT, HT, HT, stA, stB, acc);

  // ===== epilogue 2: sumsq_t, dot(s,t) =====
#pragma unroll
  for (int fr = 0; fr < 4; fr++) {
    const int r0 = wr * 64 + fr * 16 + q4;
    float st[4] = {0.f, 0.f, 0.f, 0.f}, dt[4] = {0.f, 0.f, 0.f, 0.f};
#pragma unroll
    for (int fc = 0; fc < 4; fc++) {
      f32x4 v = acc[fr][fc];
      const int cLoc = wc * 64 + fc * 16 + l15;
      u32x2 p = *(const u32x2*)&sStore[cLoc * 132 + r0];
      float sv[4];
      sv[0] = __uint_as_float(p.x << 16);
      sv[1] = __uint_as_float(p.x & 0xffff0000u);
      sv[2] = __uint_as_float(p.y << 16);
      sv[3] = __uint_as_float(p.y & 0xffff0000u);
#pragma unroll
      for (int rg = 0; rg < 4; rg++) {
        float t = v[rg];
        st[rg] += t * t;
        dt[rg] += sv[rg] * t;
      }
    }
#pragma unroll
    for (int m = 1; m < 16; m <<= 1) {
#pragma unroll
      for (int rg = 0; rg < 4; rg++) {
        st[rg] += __shfl_xor(st[rg], m, 64);
        dt[rg] += __shfl_xor(dt[rg], m, 64);
      }
    }
    if (l15 == 0) {
      size_t pbase = (size_t)(cb * 2 + wc) * BT + row0 + r0;
#pragma unroll
      for (int rg = 0; rg < 4; rg++) {
        pt[pbase + rg] = st[rg];
        pd[pbase + rg] = dt[rg];
      }
    }
  }
}

// ---------- per-row reduce over 500 column slabs ----------
__global__ void kreduce(const float* __restrict__ pe, const float* __restrict__ ps,
                        const float* __restrict__ pt, const float* __restrict__ pd,
                        const float* __restrict__ tgtLogit, const int* __restrict__ target,
                        float* __restrict__ scal) {
  int row = blockIdx.x * blockDim.x + threadIdx.x;  // 2048 threads
  float se = 0.f, ss = 0.f, st = 0.f, dt = 0.f;
  for (int j = 0; j < 500; j++) {
    int idx = j * BT + row;
    se += pe[idx];
    ss += ps[idx];
    st += pt[idx];
    dt += pd[idx];
  }
  int tgt = target[row];
  bool valid = (tgt != IGN);
  float hard = valid ? (__logf(se) - tgtLogit[row]) : 0.f;
  float cosv = dt * rsqrtf(ss + 1e-12f) * rsqrtf(st + 1e-12f);
  float soft = 1.f - cosv;
  float nv = valid ? 1.f : 0.f;
  for (int m = 1; m < 64; m <<= 1) {
    hard += __shfl_xor(hard, m, 64);
    soft += __shfl_xor(soft, m, 64);
    nv += __shfl_xor(nv, m, 64);
  }
  if ((threadIdx.x & 63) == 0) {
    atomicAdd(&scal[0], hard);
    atomicAdd(&scal[1], soft);
    atomicAdd(&scal[2], nv);
  }
}

__global__ void kfinal(const float* __restrict__ scal, float* __restrict__ out) {
  float nv = scal[2];
  out[0] = 0.5f * scal[0] / nv + 0.5f * scal[1] / nv;
}

// ---------- launch ----------
extern "C" void kernel_launch(void* const* d_in, const int* in_sizes, int n_in,
                              void* d_out, int out_size, void* d_ws, size_t ws_size,
                              hipStream_t stream) {
  const float* student = (const float*)d_in[0];
  const float* teacher = (const float*)d_in[1];
  const int* target = (const int*)d_in[2];
  const float* sW = (const float*)d_in[3];
  const float* tW = (const float*)d_in[4];
  float* out = (float*)d_out;

  char* ws = (char*)d_ws;
  // layout (bytes):
  //   sAb  : 0          .. 8,388,608   (2048x2048 bf16)
  //   tAb  : 8,388,608  .. 25,165,824  (2048x4096 bf16)
  //   pe/ps/pt/pd: 4 x 4,096,000 at 25,165,824 (500 x 2048 f32 each)
  //   tgtLogit: 41,549,824 (2048 f32)
  //   scal: 41,558,016 (3 f32)
  u16* sAb = (u16*)(ws);
  u16* tAb = (u16*)(ws + 8388608);
  float* pe = (float*)(ws + 25165824);
  float* ps = (float*)(ws + 25165824 + 4096000);
  float* pt = (float*)(ws + 25165824 + 8192000);
  float* pd = (float*)(ws + 25165824 + 12288000);
  float* tgtLogit = (float*)(ws + 41549824);
  float* scal = (float*)(ws + 41558016);

  hipMemsetAsync(scal, 0, 3 * sizeof(float), stream);

  {
    int n4 = BT * HS / 4;
    cvt_f32_bf16<<<(n4 + 255) / 256, 256, 0, stream>>>((const float4*)student, (u32x2*)sAb, n4);
  }
  {
    int n4 = BT * HT / 4;
    cvt_f32_bf16<<<(n4 + 255) / 256, 256, 0, stream>>>((const float4*)teacher, (u32x2*)tAb, n4);
  }

  kmain<<<dim3(4000), dim3(256), 0, stream>>>(sAb, tAb, sW, tW, target, pe, ps, pt, pd, tgtLogit);
  kreduce<<<dim3(8), dim3(256), 0, stream>>>(pe, ps, pt, pd, tgtLogit, target, scal);
  kfinal<<<dim3(1), dim3(1), 0, stream>>>(scal, out);
}